// Round 8
// baseline (426.299 us; speedup 1.0000x reference)
//
#include <hip/hip_runtime.h>

#define DIMV 1024
#define NHV  16
#define HDV  64
#define BV   8
#define LQV  512
#define LKV  1024
#define PSTR 1032   // sP row stride in bf16: 2064B/row -> 2-way banks max (free)

typedef __bf16 bfrag  __attribute__((ext_vector_type(8)));
typedef float  f32x4  __attribute__((ext_vector_type(4)));
typedef unsigned short u16;
typedef unsigned int   u32;
typedef unsigned long long u64;

typedef const __attribute__((address_space(1))) u32 gu32;
typedef __attribute__((address_space(3))) u32 lu32;

__device__ __forceinline__ u16 f2bf(float f) {
    u32 x = __builtin_bit_cast(u32, f);
    x = x + 0x7FFFu + ((x >> 16) & 1u);   // RNE
    return (u16)(x >> 16);
}

// async global->LDS, 16B per lane; LDS dest is wave-uniform base (+lane*16 implicit)
__device__ __forceinline__ void g2l16(const u16* g, const u16* l) {
    __builtin_amdgcn_global_load_lds(
        reinterpret_cast<gu32*>(reinterpret_cast<u64>(g)),
        reinterpret_cast<lu32*>((u32)reinterpret_cast<u64>(l)),
        16, 0, 0);
}

// merged fp32 -> bf16 (RNE) cast over 4 segments (vis, wqkv, outw, text)
__global__ __launch_bounds__(256)
void cast_all(const float* __restrict__ vis,  u16* __restrict__ vis_bf,
              const float* __restrict__ wqkv, u16* __restrict__ wqkv_bf,
              const float* __restrict__ outw, u16* __restrict__ outw_bf,
              const float* __restrict__ text, u16* __restrict__ text_bf)
{
    const int i = blockIdx.x * 256 + threadIdx.x;   // float4 index, < 4194304
    const float* src; u16* dst; int off;
    if (i < 2097152)      { src = vis;  dst = vis_bf;  off = i; }
    else if (i < 2883584) { src = wqkv; dst = wqkv_bf; off = i - 2097152; }
    else if (i < 3145728) { src = outw; dst = outw_bf; off = i - 2883584; }
    else                  { src = text; dst = text_bf; off = i - 3145728; }
    const float4 v = reinterpret_cast<const float4*>(src)[off];
    ushort4 o;
    o.x = f2bf(v.x); o.y = f2bf(v.y); o.z = f2bf(v.z); o.w = f2bf(v.w);
    reinterpret_cast<ushort4*>(dst)[off] = o;
}

// Merged Q/K/V projection GEMM. 128x128 tile, BK=64, global_load_lds staging.
// grid (160, 8): bx<32 -> Q (text, 4096 rows); bx<96 -> K (vis); else V (vis, V^T store)
__global__ __launch_bounds__(256, 2)
void qkv_gemm(const u16* __restrict__ textb, const u16* __restrict__ visb,
              const u16* __restrict__ wqkvb, const float* __restrict__ bqkv,
              u16* __restrict__ qb, u16* __restrict__ kb, u16* __restrict__ vTb)
{
    __shared__ __align__(16) u16 sA[128 * 64];
    __shared__ __align__(16) u16 sB[128 * 64];

    const int t    = threadIdx.x;
    const int lane = t & 63;
    const int w    = t >> 6;
    const int quad = lane >> 4;
    const int r    = lane & 15;
    const int wr   = (w >> 1) * 64;
    const int wc   = (w & 1) * 64;
    const int bx   = blockIdx.x;
    const int nb   = blockIdx.y * 128;

    const u16* A; const u16* W; const float* bias; u16* C; int mb, mode;
    if (bx < 32)      { A = textb; W = wqkvb;           bias = bqkv;        C = qb;  mb = bx * 128;        mode = 0; }
    else if (bx < 96) { A = visb;  W = wqkvb + 1048576; bias = bqkv + 1024; C = kb;  mb = (bx - 32) * 128; mode = 0; }
    else              { A = visb;  W = wqkvb + 2097152; bias = bqkv + 2048; C = vTb; mb = (bx - 96) * 128; mode = 1; }

    const int srow  = lane >> 3;        // 0..7
    const int skoff = (lane & 7) * 8;   // k elems

    f32x4 acc[4][4] = {};
    const u16* Abase = A + (size_t)mb * 1024 + skoff;
    const u16* Wbase = W + (size_t)nb * 1024 + skoff;

    for (int k0 = 0; k0 < 1024; k0 += 64) {
#pragma unroll
        for (int it = 0; it < 4; ++it) {
            const int c = w * 4 + it;
            const int row = c * 8 + srow;
            g2l16(Abase + (size_t)row * 1024 + k0, sA + c * 512);
            g2l16(Wbase + (size_t)row * 1024 + k0, sB + c * 512);
        }
        __syncthreads();
#pragma unroll
        for (int kk = 0; kk < 2; ++kk) {
            bfrag af[4], bg[4];
#pragma unroll
            for (int i = 0; i < 4; ++i)
                af[i] = *reinterpret_cast<const bfrag*>(sA + (wr + i * 16 + r) * 64 + kk * 32 + quad * 8);
#pragma unroll
            for (int j = 0; j < 4; ++j)
                bg[j] = *reinterpret_cast<const bfrag*>(sB + (wc + j * 16 + r) * 64 + kk * 32 + quad * 8);
#pragma unroll
            for (int i = 0; i < 4; ++i)
#pragma unroll
                for (int j = 0; j < 4; ++j)
                    acc[i][j] = __builtin_amdgcn_mfma_f32_16x16x32_bf16(af[i], bg[j], acc[i][j], 0, 0, 0);
        }
        __syncthreads();
    }

#pragma unroll
    for (int i = 0; i < 4; i++)
#pragma unroll
    for (int j = 0; j < 4; j++) {
        const int colg = nb + wc + j * 16 + r;
        const float bv = bias[colg];
#pragma unroll
        for (int reg = 0; reg < 4; reg++) {
            const int rowg = mb + wr + i * 16 + quad * 4 + reg;
            const float v = acc[i][j][reg] + bv;
            if (mode == 0) C[(size_t)rowg * 1024 + colg] = f2bf(v);
            else           C[((size_t)((rowg >> 10) << 10) + colg) * 1024 + (rowg & 1023)] = f2bf(v);
        }
    }
}

// out-proj: C fp32 = ctx @ outw^T + bias + resid. 128x128 tile, grid (32, 8).
__global__ __launch_bounds__(256, 2)
void out_gemm(const u16* __restrict__ A, const u16* __restrict__ W,
              const float* __restrict__ bias, float* __restrict__ Cout,
              const float* __restrict__ resid)
{
    __shared__ __align__(16) u16 sA[128 * 64];
    __shared__ __align__(16) u16 sB[128 * 64];

    const int t    = threadIdx.x;
    const int lane = t & 63;
    const int w    = t >> 6;
    const int quad = lane >> 4;
    const int r    = lane & 15;
    const int wr   = (w >> 1) * 64;
    const int wc   = (w & 1) * 64;
    const int mb   = blockIdx.x * 128;
    const int nb   = blockIdx.y * 128;

    const int srow  = lane >> 3;
    const int skoff = (lane & 7) * 8;

    f32x4 acc[4][4] = {};
    const u16* Abase = A + (size_t)mb * 1024 + skoff;
    const u16* Wbase = W + (size_t)nb * 1024 + skoff;

    for (int k0 = 0; k0 < 1024; k0 += 64) {
#pragma unroll
        for (int it = 0; it < 4; ++it) {
            const int c = w * 4 + it;
            const int row = c * 8 + srow;
            g2l16(Abase + (size_t)row * 1024 + k0, sA + c * 512);
            g2l16(Wbase + (size_t)row * 1024 + k0, sB + c * 512);
        }
        __syncthreads();
#pragma unroll
        for (int kk = 0; kk < 2; ++kk) {
            bfrag af[4], bg[4];
#pragma unroll
            for (int i = 0; i < 4; ++i)
                af[i] = *reinterpret_cast<const bfrag*>(sA + (wr + i * 16 + r) * 64 + kk * 32 + quad * 8);
#pragma unroll
            for (int j = 0; j < 4; ++j)
                bg[j] = *reinterpret_cast<const bfrag*>(sB + (wc + j * 16 + r) * 64 + kk * 32 + quad * 8);
#pragma unroll
            for (int i = 0; i < 4; ++i)
#pragma unroll
                for (int j = 0; j < 4; ++j)
                    acc[i][j] = __builtin_amdgcn_mfma_f32_16x16x32_bf16(af[i], bg[j], acc[i][j], 0, 0, 0);
        }
        __syncthreads();
    }

#pragma unroll
    for (int i = 0; i < 4; i++)
#pragma unroll
    for (int j = 0; j < 4; j++) {
        const int colg = nb + wc + j * 16 + r;
        const float bv = bias[colg];
#pragma unroll
        for (int reg = 0; reg < 4; reg++) {
            const int rowg = mb + wr + i * 16 + quad * 4 + reg;
            Cout[(size_t)rowg * 1024 + colg] = acc[i][j][reg] + bv + resid[(size_t)rowg * 1024 + colg];
        }
    }
}

// Attention v4: no max-subtraction (scores bounded); unnormalized exp(S) -> sP before
// the single combine barrier; normalization folded into wacc update and PV epilogue.
// 2 barriers/head. Grid (32 qtiles, 8 b, 4 head-groups), 4 heads/block.
__global__ __launch_bounds__(256, 4)
void attn_kernel(const u16* __restrict__ q, const u16* __restrict__ k,
                 const u16* __restrict__ vT, u16* __restrict__ ctx,
                 float* __restrict__ attnw)
{
    __shared__ __align__(16) u16 sP[16 * PSTR];   // 33024 B
    __shared__ float reds[64];

    const int t    = threadIdx.x;
    const int lane = t & 63;
    const int w    = t >> 6;          // 0..3
    const int quad = lane >> 4;       // 0..3
    const int r    = lane & 15;
    const int b    = blockIdx.y;
    const int q0   = blockIdx.x * 16;
    const int hg   = blockIdx.z;      // 0..3

    const int row16 = quad * 4;
    const float scale = 0.125f;       // 1/sqrt(64)

    f32x4 wacc[16] = {};

    for (int hh = 0; hh < 4; ++hh) {
        const int h = hg * 4 + hh;
        const int dbase = h * HDV + quad * 8;

        const u16* qp = q + (size_t)(b * LQV + q0 + r) * DIMV + dbase;
        const bfrag qa0 = *reinterpret_cast<const bfrag*>(qp);
        const bfrag qa1 = *reinterpret_cast<const bfrag*>(qp + 32);

        // ---- QK: wave w covers cols [256w,256w+256), scores in regs ----
        f32x4 s[16];
#pragma unroll
        for (int i = 0; i < 16; ++i) {
            const int n0 = w * 256 + i * 16;
            const u16* kp = k + (size_t)(b * LKV + n0 + r) * DIMV + dbase;
            const bfrag kb0 = *reinterpret_cast<const bfrag*>(kp);
            const bfrag kb1 = *reinterpret_cast<const bfrag*>(kp + 32);
            f32x4 a = {};
            a    = __builtin_amdgcn_mfma_f32_16x16x32_bf16(qa0, kb0, a, 0, 0, 0);
            s[i] = __builtin_amdgcn_mfma_f32_16x16x32_bf16(qa1, kb1, a, 0, 0, 0);
        }

        // ---- exp (no max-sub; scores bounded) + wave-local row sum + sP write ----
        float sw[4] = {0.f, 0.f, 0.f, 0.f};
#pragma unroll
        for (int i = 0; i < 16; ++i)
#pragma unroll
            for (int reg = 0; reg < 4; ++reg) {
                const float e = __expf(s[i][reg] * scale);
                s[i][reg] = e;
                sw[reg] += e;
                sP[(row16 + reg) * PSTR + w * 256 + i * 16 + r] = f2bf(e);
            }
#pragma unroll
        for (int reg = 0; reg < 4; ++reg)
#pragma unroll
            for (int off = 1; off < 16; off <<= 1)
                sw[reg] += __shfl_xor(sw[reg], off);
        if (r == 0) {
#pragma unroll
            for (int reg = 0; reg < 4; ++reg) reds[w * 16 + row16 + reg] = sw[reg];
        }
        __syncthreads();   // combine barrier; also makes sP visible to all waves

        float inv[4];
#pragma unroll
        for (int reg = 0; reg < 4; ++reg) {
            const int rr = row16 + reg;
            inv[reg] = 1.0f / (reds[rr] + reds[16 + rr] + reds[32 + rr] + reds[48 + rr]);
        }
        // mean-prob accumulation (normalized)
#pragma unroll
        for (int i = 0; i < 16; ++i)
#pragma unroll
            for (int reg = 0; reg < 4; ++reg)
                wacc[i][reg] += s[i][reg] * inv[reg];

        // ---- PV on unnormalized P; normalize at write. 4 independent chains ----
        {
            const int n0 = w * 16;
            f32x4 c0 = {}, c1 = {}, c2 = {}, c3 = {};
            const u16* vb = vT + (size_t)(b * DIMV + h * HDV + n0 + r) * LKV;
#pragma unroll
            for (int kk = 0; kk < LKV; kk += 128) {
                const bfrag a0 = *reinterpret_cast<const bfrag*>(&sP[r * PSTR + kk      + quad * 8]);
                const bfrag a1 = *reinterpret_cast<const bfrag*>(&sP[r * PSTR + kk + 32 + quad * 8]);
                const bfrag a2 = *reinterpret_cast<const bfrag*>(&sP[r * PSTR + kk + 64 + quad * 8]);
                const bfrag a3 = *reinterpret_cast<const bfrag*>(&sP[r * PSTR + kk + 96 + quad * 8]);
                const bfrag b0 = *reinterpret_cast<const bfrag*>(vb + kk      + quad * 8);
                const bfrag b1 = *reinterpret_cast<const bfrag*>(vb + kk + 32 + quad * 8);
                const bfrag b2 = *reinterpret_cast<const bfrag*>(vb + kk + 64 + quad * 8);
                const bfrag b3 = *reinterpret_cast<const bfrag*>(vb + kk + 96 + quad * 8);
                c0 = __builtin_amdgcn_mfma_f32_16x16x32_bf16(a0, b0, c0, 0, 0, 0);
                c1 = __builtin_amdgcn_mfma_f32_16x16x32_bf16(a1, b1, c1, 0, 0, 0);
                c2 = __builtin_amdgcn_mfma_f32_16x16x32_bf16(a2, b2, c2, 0, 0, 0);
                c3 = __builtin_amdgcn_mfma_f32_16x16x32_bf16(a3, b3, c3, 0, 0, 0);
            }
            const f32x4 c = (c0 + c1) + (c2 + c3);
#pragma unroll
            for (int reg = 0; reg < 4; ++reg)
                ctx[(size_t)(b * LQV + q0 + row16 + reg) * DIMV + h * HDV + n0 + r] = f2bf(c[reg] * inv[reg]);
        }
        __syncthreads();   // sP/reds safe for next head
    }

    // ---- attn_weights mean: add this block's 4-head sum (attnw pre-zeroed) ----
    const float inv16 = 1.0f / 16.0f;
#pragma unroll
    for (int i = 0; i < 16; ++i)
#pragma unroll
        for (int reg = 0; reg < 4; ++reg)
            atomicAdd(&attnw[(size_t)(b * LQV + q0 + row16 + reg) * LKV + w * 256 + i * 16 + r],
                      wacc[i][reg] * inv16);
}

// LayerNorm per row of 1024; x fp32 (attended+residual), g/b fp32, out fp32
__global__ __launch_bounds__(256)
void ln_kernel(const float* __restrict__ x, const float* __restrict__ g,
               const float* __restrict__ bta, float* __restrict__ out)
{
    __shared__ float red[8];
    const int row = blockIdx.x;
    const int t = threadIdx.x;
    const int w = t >> 6;
    const float4 xv = reinterpret_cast<const float4*>(x + (size_t)row * DIMV)[t];

    float s = xv.x + xv.y + xv.z + xv.w;
#pragma unroll
    for (int off = 32; off; off >>= 1) s += __shfl_down(s, off);
    if ((t & 63) == 0) red[w] = s;
    __syncthreads();
    const float mu = (red[0] + red[1] + red[2] + red[3]) * (1.0f / 1024.0f);

    const float d0 = xv.x - mu, d1 = xv.y - mu, d2 = xv.z - mu, d3 = xv.w - mu;
    float s2 = d0 * d0 + d1 * d1 + d2 * d2 + d3 * d3;
#pragma unroll
    for (int off = 32; off; off >>= 1) s2 += __shfl_down(s2, off);
    if ((t & 63) == 0) red[4 + w] = s2;
    __syncthreads();
    const float var = (red[4] + red[5] + red[6] + red[7]) * (1.0f / 1024.0f);
    const float inv = rsqrtf(var + 1e-5f);

    float4 o;
    const int c = t * 4;
    o.x = d0 * inv * g[c + 0] + bta[c + 0];
    o.y = d1 * inv * g[c + 1] + bta[c + 1];
    o.z = d2 * inv * g[c + 2] + bta[c + 2];
    o.w = d3 * inv * g[c + 3] + bta[c + 3];
    reinterpret_cast<float4*>(out + (size_t)row * DIMV)[t] = o;
}

extern "C" void kernel_launch(void* const* d_in, const int* in_sizes, int n_in,
                              void* d_out, int out_size, void* d_ws, size_t ws_size,
                              hipStream_t stream)
{
    const float* text = (const float*)d_in[0];   // (8,512,1024)
    const float* vis  = (const float*)d_in[1];   // (8,1024,1024)
    const float* wqkv = (const float*)d_in[2];   // (3072,1024)
    const float* bqkv = (const float*)d_in[3];   // (3072,)
    const float* outw = (const float*)d_in[4];   // (1024,1024)
    const float* outb = (const float*)d_in[5];   // (1024,)
    const float* lng  = (const float*)d_in[6];   // (1024,)
    const float* lnb  = (const float*)d_in[7];   // (1024,)

    // Workspace 64 MiB:
    //  0-16M : vis_bf (cast w; qkv r)      -> 0-8M ctxb (attn w; out_gemm r)
    // 16-22M : wqkv_bf (cast w; qkv r)
    // 22-24M : outw_bf (cast w; out_gemm r)
    // 24-32M : qb      (qkv w; attn r)
    // 32-48M : kb      (qkv w; attn r)     -> attb f32 (out_gemm w; ln r)
    // 48-64M : vTb     (qkv w; attn r)
    // text_bf lives in d_out's out-region (dead scratch until ln writes it).
    char* ws = (char*)d_ws;
    u16*   vis_bf  = (u16*)(ws);
    u16*   ctxb    = (u16*)(ws);
    u16*   wqkv_bf = (u16*)(ws + (size_t)(16u << 20));
    u16*   outw_bf = (u16*)(ws + (size_t)(22u << 20));
    u16*   qb      = (u16*)(ws + (size_t)(24u << 20));
    u16*   kb      = (u16*)(ws + (size_t)(32u << 20));
    float* attb    = (float*)(ws + (size_t)(32u << 20));
    u16*   vTb     = (u16*)(ws + (size_t)(48u << 20));

    float* outp  = (float*)d_out;                 // fp32 outputs: out[4M], attnw[4M]
    float* attnw = outp + (size_t)4096 * 1024;
    u16*   text_bf = (u16*)d_out;                 // scratch in out-region (8 MiB of 16)

    const dim3 blk(256);
    // stage 0: merged fp32 -> bf16 casts
    cast_all<<<dim3(16384), blk, 0, stream>>>(vis, vis_bf, wqkv, wqkv_bf, outw, outw_bf, text, text_bf);
    // stage 1: merged Q/K/V projections (1280 blocks)
    qkv_gemm<<<dim3(160, 8), blk, 0, stream>>>(text_bf, vis_bf, wqkv_bf, bqkv, qb, kb, vTb);
    // stage 2: attention; attnw zero-init then atomic mean-accumulate
    hipMemsetAsync(attnw, 0, (size_t)4096 * 1024 * sizeof(float), stream);
    attn_kernel<<<dim3(32, 8, 4), blk, 0, stream>>>(qb, kb, vTb, ctxb, attnw);
    // stage 3: attended = ctx @ out_w^T + out_b + text (fp32)
    out_gemm<<<dim3(32, 8), blk, 0, stream>>>(ctxb, outw_bf, outb, attb, text);
    // stage 4: layernorm -> out (fp32)
    ln_kernel<<<dim3(4096), blk, 0, stream>>>(attb, lng, lnb, outp);
}